// Round 2
// baseline (1416.807 us; speedup 1.0000x reference)
//
#include <hip/hip_runtime.h>

// LSTMStateEstimation: 2-layer LSTM (B=64,T=256,IN=128,H=512) + FC(512->64).
//
// r11 = r10's monotonic flags + r9's direct-fragment recurrent loads +
// RTT-shadow scheduling + shortened tail:
//  1. Recurrent h (h0 for L0, h1 for L1) loaded as per-lane fragments
//     (16x 16B sc0sc1 loads, TIE-interleaved MFMA) -- no LDS staging, no
//     sync, no bank conflicts on the critical path.  [r9-proven pattern]
//  2. L1's h0_t operand (8 steps stale) prefetched during step t-1 into
//     double-buffered LDS; its 16 MFMAs run in the h1 frag-load shadow.
//     L0's x-part MFMAs likewise fill its frag-load shadow.
//  3. Per-wave flags: each wave packs its h slice to 4B agent atomics
//     (shfl_xor pair pack), drains its own vmcnt, publishes
//     flag[li*4+wv]=t+1. Kills h_lds8 + one barrier from the tail.
//     Consumers poll 64 flag words with 64 lanes (1 load/iter/set).
//  4. rcp instead of div in gate math; hot poll (no sleep) for 512 iters.
// Exchange primitive set UNCHANGED (r4/r5-validated):
//   h loads : global_load_dwordx4 sc0 sc1 + TIE
//   h stores: 4B/8B relaxed agent atomic stores
//   flags   : relaxed agent 4B atomic store / relaxed agent poll loads
// Polls bounded (protocol bug -> visible wrong answer, never a dead GPU).

#define NB    64
#define SEQL  256
#define INF   128
#define HID   512
#define OUTN  64
#define NWG   256
#define NT    256
#define NCNT  32
#define CADD  (NWG / NCNT)
#define PBOUND 8192

typedef __attribute__((ext_vector_type(8))) short  short8;
typedef __attribute__((ext_vector_type(4))) float  floatx4;
typedef unsigned short u16;
typedef unsigned long long u64;

#define TIE8(N, x0,x1,x2,x3,x4,x5,x6,x7)                                    \
  asm volatile("s_waitcnt vmcnt(" N ")"                                     \
               : "+v"(x0), "+v"(x1), "+v"(x2), "+v"(x3),                    \
                 "+v"(x4), "+v"(x5), "+v"(x6), "+v"(x7))
#define TIE4(N, x0,x1,x2,x3)                                                \
  asm volatile("s_waitcnt vmcnt(" N ")" : "+v"(x0), "+v"(x1), "+v"(x2), "+v"(x3))
#define TIE2(N, x0,x1)                                                      \
  asm volatile("s_waitcnt vmcnt(" N ")" : "+v"(x0), "+v"(x1))

#define MFMA(ACC, A, B) \
  ACC = __builtin_amdgcn_mfma_f32_16x16x32_bf16((A), (B), ACC, 0, 0, 0)

__device__ __forceinline__ u16 f2bf(float f) {
  union { float f; unsigned u; } v; v.f = f;
  return (u16)((v.u + 0x7FFFu + ((v.u >> 16) & 1u)) >> 16);  // RNE
}
__device__ __forceinline__ float bf2f(u16 s) {
  union { unsigned u; float f; } v; v.u = ((unsigned)s) << 16;
  return v.f;
}
__device__ __forceinline__ float sigf(float v) {
  return __builtin_amdgcn_rcpf(1.f + __expf(-v));
}
__device__ __forceinline__ float tanh_fast(float v) {
  float cv = fminf(fmaxf(v, -15.f), 15.f);
  float e = __expf(2.f * cv);
  return (e - 1.f) * __builtin_amdgcn_rcpf(e + 1.f);
}

// ---- proven exchange primitives (r4/r5-validated on MI355X) ----
__device__ __forceinline__ short8 ldh(const u16* p) {
  short8 d;
  asm volatile("global_load_dwordx4 %0, %1, off sc0 sc1" : "=v"(d) : "v"(p));
  return d;
}
__device__ __forceinline__ void st8c(u16* p, u64 v) {
  __hip_atomic_store((u64*)p, v, __ATOMIC_RELAXED, __HIP_MEMORY_SCOPE_AGENT);
}
__device__ __forceinline__ void st4c(u16* p, unsigned v) {
  __hip_atomic_store((unsigned*)p, v, __ATOMIC_RELAXED, __HIP_MEMORY_SCOPE_AGENT);
}

// 64-word per-wave flag wait: lane polls f0[lane] vs thr0 and f1[lane] vs
// thr1 (thr<=0 => vacuous, no load). ALL waves call this; no barrier.
// Bounded; ends with a fence so following ldh() asm can't hoist above.
__device__ __forceinline__ void wait_ge64(const unsigned* f0, int thr0,
                                          const unsigned* f1, int thr1) {
  const int lane = threadIdx.x & 63;
  const unsigned* p0 = f0 + lane;
  const unsigned* p1 = f1 + lane;
  for (int i = 0; i < PBOUND; ++i) {
    int a = 0x7fffffff, b = 0x7fffffff;
    if (thr0 > 0) a = (int)__hip_atomic_load(p0, __ATOMIC_RELAXED,
                                             __HIP_MEMORY_SCOPE_AGENT);
    if (thr1 > 0) b = (int)__hip_atomic_load(p1, __ATOMIC_RELAXED,
                                             __HIP_MEMORY_SCOPE_AGENT);
    if (__all((a >= thr0) & (b >= thr1))) break;
    if (i > 512) __builtin_amdgcn_s_sleep(2);
  }
  __builtin_amdgcn_sched_barrier(0);
  asm volatile("" ::: "memory");
}

// One-time MALL grid barrier (r5-proven shape), bounded poll.
__device__ __forceinline__ void grid_bar_once(unsigned* leaf, int w) {
  asm volatile("s_waitcnt vmcnt(0)" ::: "memory");
  __syncthreads();
  if (threadIdx.x == 0)
    __hip_atomic_fetch_add(&leaf[(w & (NCNT - 1)) * 32], 1u, __ATOMIC_RELAXED,
                           __HIP_MEMORY_SCOPE_AGENT);
  if (threadIdx.x < 64) {
    const int lane = threadIdx.x & 63;
    for (int i = 0; i < (1 << 16); ++i) {
      unsigned v = CADD;
      if (lane < NCNT)
        v = __hip_atomic_load(&leaf[lane * 32], __ATOMIC_RELAXED,
                              __HIP_MEMORY_SCOPE_AGENT);
      if (__all(v >= CADD)) break;
      __builtin_amdgcn_s_sleep(1);
    }
  }
  __syncthreads();
}

// B-fragments: 2 n-tiles (rowid = wv*32 + t2*16 + mrow) x KS k-steps.
// rowid -> unit u = rowid>>2, gate G = rowid&3; gate-row r = G*512+32*li+u.
// K-layout = [input(KIN) | h_prev(512)].
template <int KS, int KIN>
__device__ __forceinline__ void load_B(short8 (&Bf)[2][32],
                                       const float* __restrict__ Wih,
                                       const float* __restrict__ Whh,
                                       int li, int wv, int mrow, int quad) {
#pragma unroll
  for (int t2 = 0; t2 < 2; ++t2) {
    const int rowid = wv * 32 + t2 * 16 + mrow;
    const int r = (rowid & 3) * HID + 32 * li + (rowid >> 2);
    const float* wr = Wih + (size_t)r * KIN;
    const float* hr = Whh + (size_t)r * HID - KIN;   // hr[k]=Whh[r][k-KIN]
#pragma unroll
    for (int ks = 0; ks < KS; ++ks) {
      short8 v;
#pragma unroll
      for (int j = 0; j < 8; ++j) {
        const int k = 32 * ks + quad * 8 + j;
        v[j] = (short)f2bf(k < KIN ? wr[k] : hr[k]);
      }
      Bf[t2][ks] = v;
    }
  }
}

__global__ __launch_bounds__(NT, 1) void lstm_groups(
    const float* __restrict__ x,
    const float* __restrict__ Wih0, const float* __restrict__ Whh0,
    const float* __restrict__ bih0, const float* __restrict__ bhh0,
    const float* __restrict__ Wih1, const float* __restrict__ Whh1,
    const float* __restrict__ bih1, const float* __restrict__ bhh1,
    const float* __restrict__ Wfc,  const float* __restrict__ bfc,
    float* __restrict__ out,
    unsigned* __restrict__ leaf,
    unsigned* __restrict__ flag0, unsigned* __restrict__ flag1,
    u16* __restrict__ h0r, u16* __restrict__ h1r, u16* __restrict__ xg)
{
  const int w = blockIdx.x, tid = threadIdx.x;
  const int lane = tid & 63, wv = tid >> 6;
  const int quad = lane >> 4, mrow = lane & 15;
  const int g = w & 7, m = w >> 3;          // group, member (0..31)
  const bool isL1 = (m >= 16);
  const int  li   = isL1 ? m - 16 : m;      // layer-local WG index (0..15)

  __shared__ float g_lds[128][9];
  __shared__ float bias_lds[128];
  __shared__ float red[16][17];
  // L1 h0 prefetch: 2 buffers x [b(8)][k(512)] bf16, XOR-swizzled b<<4.
  __shared__ short8 hA2[2][512];
  char* hAc = (char*)hA2;

  // ---- xg fill: xg[g][t][b][k] bf16, 8 (g,t)-slices per WG, MALL stores ----
#pragma unroll
  for (int i = 0; i < 8; ++i) {
    const int s = w * 8 + i, gs = s >> 8, ts = s & 255;
    u16* dst = xg + (size_t)(gs * 256 + ts) * 1024;
    const int b = tid >> 5, k0 = (tid & 31) * 4;
    const float* src = x + ((size_t)(8 * gs + b) * SEQL + ts) * INF + k0;
    union { u16 h[4]; u64 u; } pk;
#pragma unroll
    for (int j = 0; j < 4; ++j) pk.h[j] = f2bf(src[j]);
    st8c(dst + b * 128 + k0, pk.u);
  }

  // ---- weights -> VGPR B-fragments; bias -> LDS ----
  short8 Bf[2][32];
  if (isL1) load_B<32, HID>(Bf, Wih1, Whh1, li, wv, mrow, quad);
  else      load_B<20, INF>(Bf, Wih0, Whh0, li, wv, mrow, quad);
  if (tid < 128) {
    const int r = (tid & 3) * HID + 32 * li + (tid >> 2);
    bias_lds[tid] = (isL1 ? bih1[r] + bhh1[r] : bih0[r] + bhh0[r]);
  }

  grid_bar_once(leaf, w);   // xg complete everywhere; rings/flags zeroed

  // per-wave monotonic flags: flag[g*64 + li*4 + wv] = t+1
  unsigned* flag0g = flag0 + g * 64;
  unsigned* flag1g = flag1 + g * 64;
  u16* h0g = h0r + (size_t)g * 32768;       // 8 slots x 8 b x 512 k
  u16* h1g = h1r + (size_t)g * 32768;
  const u16* xgg = xg + (size_t)g * 256 * 1024;

  float cst = 0.f;                 // fp32 cell state, thread-private
  const int ab = mrow & 7;         // batch of this lane's A row (dup 8..15)
  const int koff = quad * 8;

  // staging LDS offsets for this thread (granule tid and tid+256)
  const int so0 = (tid * 16) ^ ((tid >> 6) << 4);
  const int so1 = ((tid + 256) * 16) ^ (((tid + 256) >> 6) << 4);

  // L1 pre-stage: h0[0] -> hA2 buf0 (slot 0), gated on flag0 >= 1
  if (isL1) {
    wait_ge64(flag0g, 1, flag0g, 0);
    short8 s0 = ldh(h0g + tid * 8);
    short8 s1 = ldh(h0g + (tid + 256) * 8);
    TIE2("0", s0, s1);
    *(short8*)(hAc + so0) = s0;
    *(short8*)(hAc + so1) = s1;
    __syncthreads();
  }

  for (int t = 0; t < SEQL; ++t) {
    floatx4 a00 = {0,0,0,0}, a01 = {0,0,0,0}, a10 = {0,0,0,0}, a11 = {0,0,0,0};
    short8 f0,f1,f2,f3,f4,f5,f6,f7,f8,f9,f10,f11,f12,f13,f14,f15;

    if (!isL1) {
      // x-part operands (cached xg) issued before the wait
      const u16* xa = xgg + (size_t)t * 1024 + ab * 128 + koff;
      short8 x0 = *(const short8*)(xa +  0);
      short8 x1 = *(const short8*)(xa + 32);
      short8 x2 = *(const short8*)(xa + 64);
      short8 x3 = *(const short8*)(xa + 96);

      // peers done t-1 (flag>=t); L1 consumed h0[t-8] (flag1>=t-7, ring WAR)
      wait_ge64(flag0g, t, flag1g, t - 7);

      // recurrent h0_{t-1}: direct per-lane fragments, one RTT, shadowed
      const u16* ha = h0g + ((t + 7) & 7) * 4096 + ab * 512 + koff;
      f0=ldh(ha+0);    f1=ldh(ha+32);   f2=ldh(ha+64);   f3=ldh(ha+96);
      f4=ldh(ha+128);  f5=ldh(ha+160);  f6=ldh(ha+192);  f7=ldh(ha+224);
      f8=ldh(ha+256);  f9=ldh(ha+288);  f10=ldh(ha+320); f11=ldh(ha+352);
      f12=ldh(ha+384); f13=ldh(ha+416); f14=ldh(ha+448); f15=ldh(ha+480);

      // x-part MFMAs fill the load shadow
      MFMA(a00,x0,Bf[0][0]);  MFMA(a10,x0,Bf[1][0]);
      MFMA(a01,x1,Bf[0][1]);  MFMA(a11,x1,Bf[1][1]);
      MFMA(a00,x2,Bf[0][2]);  MFMA(a10,x2,Bf[1][2]);
      MFMA(a01,x3,Bf[0][3]);  MFMA(a11,x3,Bf[1][3]);

      TIE8("8", f0,f1,f2,f3,f4,f5,f6,f7);
      MFMA(a00,f0,Bf[0][4]);  MFMA(a10,f0,Bf[1][4]);
      MFMA(a01,f1,Bf[0][5]);  MFMA(a11,f1,Bf[1][5]);
      MFMA(a00,f2,Bf[0][6]);  MFMA(a10,f2,Bf[1][6]);
      MFMA(a01,f3,Bf[0][7]);  MFMA(a11,f3,Bf[1][7]);
      MFMA(a00,f4,Bf[0][8]);  MFMA(a10,f4,Bf[1][8]);
      MFMA(a01,f5,Bf[0][9]);  MFMA(a11,f5,Bf[1][9]);
      MFMA(a00,f6,Bf[0][10]); MFMA(a10,f6,Bf[1][10]);
      MFMA(a01,f7,Bf[0][11]); MFMA(a11,f7,Bf[1][11]);
      TIE8("0", f8,f9,f10,f11,f12,f13,f14,f15);
      MFMA(a00,f8, Bf[0][12]); MFMA(a10,f8, Bf[1][12]);
      MFMA(a01,f9, Bf[0][13]); MFMA(a11,f9, Bf[1][13]);
      MFMA(a00,f10,Bf[0][14]); MFMA(a10,f10,Bf[1][14]);
      MFMA(a01,f11,Bf[0][15]); MFMA(a11,f11,Bf[1][15]);
      MFMA(a00,f12,Bf[0][16]); MFMA(a10,f12,Bf[1][16]);
      MFMA(a01,f13,Bf[0][17]); MFMA(a11,f13,Bf[1][17]);
      MFMA(a00,f14,Bf[0][18]); MFMA(a10,f14,Bf[1][18]);
      MFMA(a01,f15,Bf[0][19]); MFMA(a11,f15,Bf[1][19]);
    } else {
      // L0 has h0_t ready (flag0>=t+2 also gates next prefetch, clamped);
      // peers done t-1 (flag1>=t, also h1-ring WAR safe)
      const int thr0 = (t + 2 < 256) ? (t + 2) : 256;
      wait_ge64(flag0g, thr0, flag1g, t);

      // recurrent h1_{t-1}: direct per-lane fragments (critical RTT)
      const u16* hb = h1g + ((t + 7) & 7) * 4096 + ab * 512 + koff;
      f0=ldh(hb+0);    f1=ldh(hb+32);   f2=ldh(hb+64);   f3=ldh(hb+96);
      f4=ldh(hb+128);  f5=ldh(hb+160);  f6=ldh(hb+192);  f7=ldh(hb+224);
      f8=ldh(hb+256);  f9=ldh(hb+288);  f10=ldh(hb+320); f11=ldh(hb+352);
      f12=ldh(hb+384); f13=ldh(hb+416); f14=ldh(hb+448); f15=ldh(hb+480);
      // prefetch h0[t+1] stage granules (consumed next iter)
      const u16* sp = h0g + ((t + 1) & 7) * 4096;
      short8 s0 = ldh(sp + tid * 8);
      short8 s1 = ldh(sp + (tid + 256) * 8);

      // h0_t-part MFMAs from prefetched LDS fill the h1 load shadow
      const char* hc = hAc + (t & 1) * 8192;
#pragma unroll
      for (int n = 0; n < 16; ++n) {
        const short8 fv = *(const short8*)(
            hc + ((ab * 1024 + n * 64 + quad * 16) ^ (ab << 4)));
        if ((n & 1) == 0) { MFMA(a00, fv, Bf[0][n]); MFMA(a10, fv, Bf[1][n]); }
        else              { MFMA(a01, fv, Bf[0][n]); MFMA(a11, fv, Bf[1][n]); }
      }

      TIE8("10", f0,f1,f2,f3,f4,f5,f6,f7);
      MFMA(a00,f0,Bf[0][16]); MFMA(a10,f0,Bf[1][16]);
      MFMA(a01,f1,Bf[0][17]); MFMA(a11,f1,Bf[1][17]);
      MFMA(a00,f2,Bf[0][18]); MFMA(a10,f2,Bf[1][18]);
      MFMA(a01,f3,Bf[0][19]); MFMA(a11,f3,Bf[1][19]);
      MFMA(a00,f4,Bf[0][20]); MFMA(a10,f4,Bf[1][20]);
      MFMA(a01,f5,Bf[0][21]); MFMA(a11,f5,Bf[1][21]);
      MFMA(a00,f6,Bf[0][22]); MFMA(a10,f6,Bf[1][22]);
      MFMA(a01,f7,Bf[0][23]); MFMA(a11,f7,Bf[1][23]);
      TIE8("2", f8,f9,f10,f11,f12,f13,f14,f15);
      MFMA(a00,f8, Bf[0][24]); MFMA(a10,f8, Bf[1][24]);
      MFMA(a01,f9, Bf[0][25]); MFMA(a11,f9, Bf[1][25]);
      MFMA(a00,f10,Bf[0][26]); MFMA(a10,f10,Bf[1][26]);
      MFMA(a01,f11,Bf[0][27]); MFMA(a11,f11,Bf[1][27]);
      MFMA(a00,f12,Bf[0][28]); MFMA(a10,f12,Bf[1][28]);
      MFMA(a01,f13,Bf[0][29]); MFMA(a11,f13,Bf[1][29]);
      MFMA(a00,f14,Bf[0][30]); MFMA(a10,f14,Bf[1][30]);
      MFMA(a01,f15,Bf[0][31]); MFMA(a11,f15,Bf[1][31]);

      // stage -> LDS buf (t+1)&1 (read next iter, after the barrier below)
      TIE2("0", s0, s1);
      *(short8*)(hAc + ((t + 1) & 1) * 8192 + so0) = s0;
      *(short8*)(hAc + ((t + 1) & 1) * 8192 + so1) = s1;
    }

    const floatx4 accA = a00 + a01, accB = a10 + a11;
    // D layout: col(lane&15)->rowid-in-tile, row(quad*4+reg)->batch (0-7 real)
    if (quad < 2) {
#pragma unroll
      for (int r = 0; r < 4; ++r) {
        g_lds[wv * 32 + mrow][quad * 4 + r]      = accA[r];
        g_lds[wv * 32 + 16 + mrow][quad * 4 + r] = accB[r];
      }
    }
    __syncthreads();

    {  // gate math: thread -> (batch b, unit u); c stays in a register
      const int u = tid & 31, b = tid >> 5;
      const float gi = g_lds[u * 4 + 0][b] + bias_lds[u * 4 + 0];
      const float gf = g_lds[u * 4 + 1][b] + bias_lds[u * 4 + 1];
      const float gg = g_lds[u * 4 + 2][b] + bias_lds[u * 4 + 2];
      const float go = g_lds[u * 4 + 3][b] + bias_lds[u * 4 + 3];
      const float c = sigf(gf) * cst + sigf(gi) * tanh_fast(gg);
      cst = c;
      // pack (u, u+1) pair via shfl_xor; even-u lane stores 4B atomic
      unsigned hv = (unsigned)f2bf(sigf(go) * tanh_fast(c));
      unsigned ov = (unsigned)__shfl_xor((int)hv, 1);
      if ((u & 1) == 0) {
        u16* dst = (isL1 ? h1g : h0g) + (t & 7) * 4096 + b * 512 + li * 32 + u;
        st4c(dst, hv | (ov << 16));
      }
    }
    // per-wave drain + per-wave flag publish (no trailing barrier)
    asm volatile("s_waitcnt vmcnt(0)" ::: "memory");
    if (lane == 0)
      __hip_atomic_store((isL1 ? flag1g : flag0g) + li * 4 + wv,
                         (unsigned)(t + 1),
                         __ATOMIC_RELAXED, __HIP_MEMORY_SCOPE_AGENT);
  }

  // ---- FC head: out[b][o] = h1_255[b] . Wfc[o] + bfc[o] ----
  wait_ge64(flag1g, 256, flag1g, 0);   // all L1 producer waves done t=255
  {
    const int bloc = m >> 2, oq = m & 3;    // 32 members = 8 b x 4 o-blocks
    const int ol = tid >> 4, ksub = tid & 15;
    const u16* hp = h1g + 7 * 4096 + bloc * 512 + ksub * 32;
    short8 v0 = ldh(hp),      v1 = ldh(hp + 8);
    short8 v2 = ldh(hp + 16), v3 = ldh(hp + 24);
    TIE4("0", v0, v1, v2, v3);
    const float* wr = Wfc + (size_t)(oq * 16 + ol) * HID + ksub * 32;
    float s = 0.f;
#pragma unroll
    for (int j = 0; j < 8; ++j) {
      s += bf2f((u16)v0[j]) * wr[j];
      s += bf2f((u16)v1[j]) * wr[8 + j];
      s += bf2f((u16)v2[j]) * wr[16 + j];
      s += bf2f((u16)v3[j]) * wr[24 + j];
    }
    red[ol][ksub] = s;
    __syncthreads();
    if (tid < 16) {
      float sum = 0.f;
#pragma unroll
      for (int j = 0; j < 16; ++j) sum += red[tid][j];
      out[(size_t)(8 * g + bloc) * OUTN + oq * 16 + tid] = sum + bfc[oq * 16 + tid];
    }
  }
}

// Workspace layout (bytes):
//   [256, 4352)          one-time barrier leaves (32 x 128B)
//   [8192, 10240)        flag0[8][64] u32 (per-wave monotonic)
//   [16384, 18432)       flag1[8][64] u32
//   [32768, 557056)      h0 rings: 8 groups x 8 slots x 8 b x 512 k bf16
//   [557056, 1081344)    h1 rings
//   [1081344, 5275648)   xg: 8 groups x 256 t x 8 b x 128 k bf16
// memset [0, 1081344) each launch (flags/rings; slot 7 = h[-1] = 0).

extern "C" void kernel_launch(void* const* d_in, const int* in_sizes, int n_in,
                              void* d_out, int out_size, void* d_ws, size_t ws_size,
                              hipStream_t stream) {
  (void)in_sizes; (void)n_in; (void)out_size; (void)ws_size;

  char* ws = (char*)d_ws;
  unsigned* leaf  = (unsigned*)(ws + 256);
  unsigned* flag0 = (unsigned*)(ws + 8192);
  unsigned* flag1 = (unsigned*)(ws + 16384);
  u16* h0r = (u16*)(ws + 32768);
  u16* h1r = (u16*)(ws + 557056);
  u16* xg  = (u16*)(ws + 1081344);

  hipMemsetAsync(d_ws, 0, 1081344, stream);

  const float* x    = (const float*)d_in[0];
  const float* Wih0 = (const float*)d_in[1];
  const float* Whh0 = (const float*)d_in[2];
  const float* bih0 = (const float*)d_in[3];
  const float* bhh0 = (const float*)d_in[4];
  const float* Wih1 = (const float*)d_in[5];
  const float* Whh1 = (const float*)d_in[6];
  const float* bih1 = (const float*)d_in[7];
  const float* bhh1 = (const float*)d_in[8];
  const float* Wfc  = (const float*)d_in[9];
  const float* bfc  = (const float*)d_in[10];
  float* out = (float*)d_out;

  void* args[] = {
    (void*)&x,
    (void*)&Wih0, (void*)&Whh0, (void*)&bih0, (void*)&bhh0,
    (void*)&Wih1, (void*)&Whh1, (void*)&bih1, (void*)&bhh1,
    (void*)&Wfc,  (void*)&bfc,
    (void*)&out,
    (void*)&leaf, (void*)&flag0, (void*)&flag1,
    (void*)&h0r, (void*)&h1r, (void*)&xg
  };
  hipError_t err = hipLaunchCooperativeKernel((const void*)lstm_groups,
                                              dim3(NWG), dim3(NT), args, 0, stream);
  if (err != hipSuccess) {
    // 256 blocks @ 1 block/CU on 256 CUs are co-resident structurally.
    hipLaunchKernelGGL(lstm_groups, dim3(NWG), dim3(NT), 0, stream,
                       x, Wih0, Whh0, bih0, bhh0, Wih1, Whh1, bih1, bhh1,
                       Wfc, bfc, out, leaf, flag0, flag1, h0r, h1r, xg);
  }
}

// Round 3
// 1070.334 us; speedup vs baseline: 1.3237x; 1.3237x over previous
//
#include <hip/hip_runtime.h>

// LSTMStateEstimation: 2-layer LSTM (B=64,T=256,IN=128,H=512) + FC(512->64).
//
// r12 = r10 skeleton (the 1142us best) + two surgical changes.
// Post-mortem r11: direct per-lane fragment loads made all 4 waves load the
// identical operand set (64 coherent loads/WG-step, ~1.6 TB/s MALL read
// traffic) -> congestion inflated every latency hop; 1375us. r10's
// once-per-WG staging (2 loads/thread) is restored everywhere.
// Changes vs r10:
//  1. L1 h0 DOUBLE-BUFFER PREFETCH: during step t, prefetch h0[t+1] into
//     LDS (gated flag0>=t+2, free at the steady-state lead of 8 enforced
//     by the ring-8 WAR gate). Step t computes the h0 half from LDS with
//     NO global RTT; the only on-path coherent loads (h1[t-1], 2/thread)
//     fly in the shadow of those 32 MFMAs.
//  2. rcp instead of div in gate math (r11-validated, same absmax).
// Everything else EXACTLY r10: per-WG monotonic flags (store t+1, no RMW),
// 16+16-lane sleepy poll, h_lds8 pack + wave0 8B agent-atomic stores,
// single vmcnt(0) drain + single flag store per WG-step.
// Exchange primitive set UNCHANGED (r4/r5-validated):
//   h loads : global_load_dwordx4 sc0 sc1 + TIE
//   h stores: 8B relaxed agent atomic stores
//   flags   : relaxed agent 4B atomic store / relaxed agent poll loads
// Polls bounded (protocol bug -> visible wrong answer, never a dead GPU).

#define NB    64
#define SEQL  256
#define INF   128
#define HID   512
#define OUTN  64
#define NWG   256
#define NT    256
#define NCNT  32
#define CADD  (NWG / NCNT)
#define PBOUND 4096

typedef __attribute__((ext_vector_type(8))) short  short8;
typedef __attribute__((ext_vector_type(4))) float  floatx4;
typedef unsigned short u16;
typedef unsigned long long u64;

#define TIE4(N, x0,x1,x2,x3)                                                \
  asm volatile("s_waitcnt vmcnt(" N ")" : "+v"(x0), "+v"(x1), "+v"(x2), "+v"(x3))
#define TIE2(N, x0,x1)                                                      \
  asm volatile("s_waitcnt vmcnt(" N ")" : "+v"(x0), "+v"(x1))

#define MFMA(ACC, A, B) \
  ACC = __builtin_amdgcn_mfma_f32_16x16x32_bf16((A), (B), ACC, 0, 0, 0)

__device__ __forceinline__ u16 f2bf(float f) {
  union { float f; unsigned u; } v; v.f = f;
  return (u16)((v.u + 0x7FFFu + ((v.u >> 16) & 1u)) >> 16);  // RNE
}
__device__ __forceinline__ float bf2f(u16 s) {
  union { unsigned u; float f; } v; v.u = ((unsigned)s) << 16;
  return v.f;
}
__device__ __forceinline__ float sigf(float v) {
  return __builtin_amdgcn_rcpf(1.f + __expf(-v));
}
__device__ __forceinline__ float tanh_fast(float v) {
  float cv = fminf(fmaxf(v, -15.f), 15.f);
  float e = __expf(2.f * cv);
  return (e - 1.f) * __builtin_amdgcn_rcpf(e + 1.f);
}

// ---- proven exchange primitives (r4/r5-validated on MI355X) ----
__device__ __forceinline__ short8 ldh(const u16* p) {
  short8 d;
  asm volatile("global_load_dwordx4 %0, %1, off sc0 sc1" : "=v"(d) : "v"(p));
  return d;
}
__device__ __forceinline__ void st8c(u16* p, u64 v) {
  __hip_atomic_store((u64*)p, v, __ATOMIC_RELAXED, __HIP_MEMORY_SCOPE_AGENT);
}

// Per-producer flag wait: lanes 0-15 poll f0[0..15] vs thr0, lanes 16-31
// poll f1[0..15] vs thr1 (thr<=0 => vacuous). ALL waves call this; no
// barrier inside. Bounded. Ends with a fence so the following staged
// ldh() asm cannot hoist above the poll.
__device__ __forceinline__ void wait_ge(const unsigned* f0, int thr0,
                                        const unsigned* f1, int thr1) {
  const int lane = threadIdx.x & 63;
  const unsigned* fp = nullptr;
  int thr = 0;
  if (lane < 16)      { fp = f0 + lane;        thr = thr0; }
  else if (lane < 32) { fp = f1 + (lane - 16); thr = thr1; }
  if (thr <= 0) fp = nullptr;
  for (int i = 0; i < PBOUND; ++i) {
    int v = 0x7fffffff;
    if (fp) v = (int)__hip_atomic_load(fp, __ATOMIC_RELAXED,
                                       __HIP_MEMORY_SCOPE_AGENT);
    if (__all(v >= thr)) break;
    if (i > 24) __builtin_amdgcn_s_sleep(1);
  }
  __builtin_amdgcn_sched_barrier(0);
  asm volatile("" ::: "memory");
}

// One-time MALL grid barrier (r5-proven shape), bounded poll.
__device__ __forceinline__ void grid_bar_once(unsigned* leaf, int w) {
  asm volatile("s_waitcnt vmcnt(0)" ::: "memory");
  __syncthreads();
  if (threadIdx.x == 0)
    __hip_atomic_fetch_add(&leaf[(w & (NCNT - 1)) * 32], 1u, __ATOMIC_RELAXED,
                           __HIP_MEMORY_SCOPE_AGENT);
  if (threadIdx.x < 64) {
    const int lane = threadIdx.x & 63;
    for (int i = 0; i < (1 << 16); ++i) {
      unsigned v = CADD;
      if (lane < NCNT)
        v = __hip_atomic_load(&leaf[lane * 32], __ATOMIC_RELAXED,
                              __HIP_MEMORY_SCOPE_AGENT);
      if (__all(v >= CADD)) break;
      __builtin_amdgcn_s_sleep(1);
    }
  }
  __syncthreads();
}

// B-fragments: 2 n-tiles (rowid = wv*32 + t2*16 + mrow) x KS k-steps.
// rowid -> unit u = rowid>>2, gate G = rowid&3; gate-row r = G*512+32*li+u.
// K-layout = [input(KIN) | h_prev(512)].
template <int KS, int KIN>
__device__ __forceinline__ void load_B(short8 (&Bf)[2][32],
                                       const float* __restrict__ Wih,
                                       const float* __restrict__ Whh,
                                       int li, int wv, int mrow, int quad) {
#pragma unroll
  for (int t2 = 0; t2 < 2; ++t2) {
    const int rowid = wv * 32 + t2 * 16 + mrow;
    const int r = (rowid & 3) * HID + 32 * li + (rowid >> 2);
    const float* wr = Wih + (size_t)r * KIN;
    const float* hr = Whh + (size_t)r * HID - KIN;   // hr[k]=Whh[r][k-KIN]
#pragma unroll
    for (int ks = 0; ks < KS; ++ks) {
      short8 v;
#pragma unroll
      for (int j = 0; j < 8; ++j) {
        const int k = 32 * ks + quad * 8 + j;
        v[j] = (short)f2bf(k < KIN ? wr[k] : hr[k]);
      }
      Bf[t2][ks] = v;
    }
  }
}

__global__ __launch_bounds__(NT, 1) void lstm_groups(
    const float* __restrict__ x,
    const float* __restrict__ Wih0, const float* __restrict__ Whh0,
    const float* __restrict__ bih0, const float* __restrict__ bhh0,
    const float* __restrict__ Wih1, const float* __restrict__ Whh1,
    const float* __restrict__ bih1, const float* __restrict__ bhh1,
    const float* __restrict__ Wfc,  const float* __restrict__ bfc,
    float* __restrict__ out,
    unsigned* __restrict__ leaf,
    unsigned* __restrict__ flag0, unsigned* __restrict__ flag1,
    u16* __restrict__ h0r, u16* __restrict__ h1r, u16* __restrict__ xg)
{
  const int w = blockIdx.x, tid = threadIdx.x;
  const int lane = tid & 63, wv = tid >> 6;
  const int quad = lane >> 4, mrow = lane & 15;
  const int g = w & 7, m = w >> 3;          // group, member (0..31)
  const bool isL1 = (m >= 16);
  const int  li   = isL1 ? m - 16 : m;      // layer-local WG index (0..15)

  __shared__ float g_lds[128][9];
  __shared__ u64   h_lds8[8][8];
  __shared__ float bias_lds[128];
  __shared__ float red[16][17];
  // staging: [b(8)][k(512)] bf16 = 8KB each, XOR-swizzled: byte ^= (b&7)<<4.
  // hA2: L1's h0 prefetch double-buffer (L0 uses buffer 0 only); hB: h1.
  __shared__ short8 hA2[2][512];
  __shared__ short8 hB[512];
  char* hAc = (char*)hA2;
  char* hBc = (char*)hB;

  // ---- xg fill: xg[g][t][b][k] bf16, 8 (g,t)-slices per WG, MALL stores ----
#pragma unroll
  for (int i = 0; i < 8; ++i) {
    const int s = w * 8 + i, gs = s >> 8, ts = s & 255;
    u16* dst = xg + (size_t)(gs * 256 + ts) * 1024;
    const int b = tid >> 5, k0 = (tid & 31) * 4;
    const float* src = x + ((size_t)(8 * gs + b) * SEQL + ts) * INF + k0;
    union { u16 h[4]; u64 u; } pk;
#pragma unroll
    for (int j = 0; j < 4; ++j) pk.h[j] = f2bf(src[j]);
    st8c(dst + b * 128 + k0, pk.u);
  }

  // ---- weights -> VGPR B-fragments; bias -> LDS ----
  short8 Bf[2][32];
  if (isL1) load_B<32, HID>(Bf, Wih1, Whh1, li, wv, mrow, quad);
  else      load_B<20, INF>(Bf, Wih0, Whh0, li, wv, mrow, quad);
  if (tid < 128) {
    const int r = (tid & 3) * HID + 32 * li + (tid >> 2);
    bias_lds[tid] = (isL1 ? bih1[r] + bhh1[r] : bih0[r] + bhh0[r]);
  }

  grid_bar_once(leaf, w);   // xg complete everywhere; rings/flags zeroed

  // per-producer flags: flag[g*64 + p], p = producer li (monotonic t+1)
  unsigned* flag0g = flag0 + g * 64;
  unsigned* flag1g = flag1 + g * 64;
  u16* h0g = h0r + (size_t)g * 32768;       // 8 slots x 8 b x 512 k
  u16* h1g = h1r + (size_t)g * 32768;
  const u16* xgg = xg + (size_t)g * 256 * 1024;

  float cst = 0.f;                 // fp32 cell state, thread-private
  const int ab = mrow & 7;         // batch of this lane's A row (dup 8..15)
  const int koff = quad * 8;

  // staging LDS offsets for this thread (granule tid and tid+256)
  const int so0 = (tid * 16) ^ ((tid >> 6) << 4);
  const int so1 = ((tid + 256) * 16) ^ (((tid + 256) >> 6) << 4);

  // L1 pre-stage: h0[0] -> hA2 buf0 (slot 0), gated on flag0 >= 1
  if (isL1) {
    wait_ge(flag0g, 1, flag0g, 0);
    short8 s0 = ldh(h0g + tid * 8);
    short8 s1 = ldh(h0g + (tid + 256) * 8);
    TIE2("0", s0, s1);
    *(short8*)(hAc + so0) = s0;
    *(short8*)(hAc + so1) = s1;
    __syncthreads();
  }

  for (int t = 0; t < SEQL; ++t) {
    floatx4 a00 = {0,0,0,0}, a01 = {0,0,0,0}, a10 = {0,0,0,0}, a11 = {0,0,0,0};

    if (!isL1) {
      // ---- x-part first: cached xg loads + 8 MFMAs, independent of flags --
      const u16* xa = xgg + (size_t)t * 1024 + ab * 128 + koff;
      short8 x0 = *(const short8*)(xa +  0);
      short8 x1 = *(const short8*)(xa + 32);
      short8 x2 = *(const short8*)(xa + 64);
      short8 x3 = *(const short8*)(xa + 96);
      MFMA(a00,x0,Bf[0][0]);  MFMA(a10,x0,Bf[1][0]);
      MFMA(a01,x1,Bf[0][1]);  MFMA(a11,x1,Bf[1][1]);
      MFMA(a00,x2,Bf[0][2]);  MFMA(a10,x2,Bf[1][2]);
      MFMA(a01,x3,Bf[0][3]);  MFMA(a11,x3,Bf[1][3]);

      // peers done t-1 (flag>=t); L1 consumed h0[t-8] (flag1>=t-7, ring WAR)
      wait_ge(flag0g, t, flag1g, t - 7);

      // ---- stage h0_{t-1} (8KB) once per WG into swizzled LDS ----
      const u16* src = h0g + ((t + 7) & 7) * 4096;
      short8 s0 = ldh(src + tid * 8);
      short8 s1 = ldh(src + (tid + 256) * 8);
      TIE2("0", s0, s1);
      *(short8*)(hAc + so0) = s0;
      *(short8*)(hAc + so1) = s1;
      __syncthreads();

#pragma unroll
      for (int n = 0; n < 16; ++n) {
        const short8 fv = *(const short8*)(
            hAc + ((ab * 1024 + n * 64 + quad * 16) ^ (ab << 4)));
        if ((n & 1) == 0) { MFMA(a00, fv, Bf[0][4 + n]); MFMA(a10, fv, Bf[1][4 + n]); }
        else              { MFMA(a01, fv, Bf[0][4 + n]); MFMA(a11, fv, Bf[1][4 + n]); }
      }
    } else {
      // L0 done t+1 (gates this step's h0[t+1] prefetch; free at lead-8
      // steady state); peers done t-1 (flag1>=t, also h1-ring WAR safe)
      const int thr0 = (t + 2 < 256) ? (t + 2) : 256;
      wait_ge(flag0g, thr0, flag1g, t);

      // on-path stage: h1_{t-1}; prefetch: h0_{t+1} (consumed next iter)
      const u16* srcB = h1g + ((t + 7) & 7) * 4096;
      const u16* srcP = h0g + ((t + 1) & 7) * 4096;
      short8 sb0 = ldh(srcB + tid * 8);
      short8 sb1 = ldh(srcB + (tid + 256) * 8);
      short8 sp0 = ldh(srcP + tid * 8);
      short8 sp1 = ldh(srcP + (tid + 256) * 8);

      // h0_t half from PREFETCHED LDS: no global RTT, fills the load shadow
      const char* hc = hAc + (t & 1) * 8192;
#pragma unroll
      for (int n = 0; n < 16; ++n) {
        const short8 fv = *(const short8*)(
            hc + ((ab * 1024 + n * 64 + quad * 16) ^ (ab << 4)));
        if ((n & 1) == 0) { MFMA(a00, fv, Bf[0][n]); MFMA(a10, fv, Bf[1][n]); }
        else              { MFMA(a01, fv, Bf[0][n]); MFMA(a11, fv, Bf[1][n]); }
      }

      TIE2("2", sb0, sb1);        // h1 staged granules ready; prefetch flies
      *(short8*)(hBc + so0) = sb0;
      *(short8*)(hBc + so1) = sb1;
      __syncthreads();

#pragma unroll
      for (int n = 0; n < 16; ++n) {
        const short8 fv = *(const short8*)(
            hBc + ((ab * 1024 + n * 64 + quad * 16) ^ (ab << 4)));
        if ((n & 1) == 0) { MFMA(a00, fv, Bf[0][16 + n]); MFMA(a10, fv, Bf[1][16 + n]); }
        else              { MFMA(a01, fv, Bf[0][16 + n]); MFMA(a11, fv, Bf[1][16 + n]); }
      }

      TIE2("0", sp0, sp1);        // land the h0[t+1] prefetch
      *(short8*)(hAc + ((t + 1) & 1) * 8192 + so0) = sp0;
      *(short8*)(hAc + ((t + 1) & 1) * 8192 + so1) = sp1;
    }

    const floatx4 accA = a00 + a01, accB = a10 + a11;
    // D layout: col(lane&15)->rowid-in-tile, row(quad*4+reg)->batch (0-7 real)
    if (quad < 2) {
#pragma unroll
      for (int r = 0; r < 4; ++r) {
        g_lds[wv * 32 + mrow][quad * 4 + r]      = accA[r];
        g_lds[wv * 32 + 16 + mrow][quad * 4 + r] = accB[r];
      }
    }
    __syncthreads();

    {  // gate math: thread -> (batch b, unit u); c stays in a register
      const int u = tid & 31, b = tid >> 5;
      const float gi = g_lds[u * 4 + 0][b] + bias_lds[u * 4 + 0];
      const float gf = g_lds[u * 4 + 1][b] + bias_lds[u * 4 + 1];
      const float gg = g_lds[u * 4 + 2][b] + bias_lds[u * 4 + 2];
      const float go = g_lds[u * 4 + 3][b] + bias_lds[u * 4 + 3];
      const float c = sigf(gf) * cst + sigf(gi) * tanh_fast(gg);
      cst = c;
      ((u16*)&h_lds8[b][0])[u] = f2bf(sigf(go) * tanh_fast(c));
    }
    __syncthreads();

    if (tid < 64) {   // 8B MALL-coherent stores: 4 units each
      const int b = tid >> 3, u8 = tid & 7;
      const u64 v = h_lds8[b][u8];
      u16* dst = (isL1 ? h1g : h0g) + (t & 7) * 4096 + b * 512 + li * 32 + u8 * 4;
      st8c(dst, v);
    }
    asm volatile("s_waitcnt vmcnt(0)" ::: "memory");   // h in MALL before flag
    if (tid == 0)
      __hip_atomic_store((isL1 ? flag1g : flag0g) + li, (unsigned)(t + 1),
                         __ATOMIC_RELAXED, __HIP_MEMORY_SCOPE_AGENT);
  }

  // ---- FC head: out[b][o] = h1_255[b] . Wfc[o] + bfc[o] ----
  wait_ge(flag1g, 256, flag1g, 0);   // all L1 producers done t=255
  {
    const int bloc = m >> 2, oq = m & 3;    // 32 members = 8 b x 4 o-blocks
    const int ol = tid >> 4, ksub = tid & 15;
    const u16* hp = h1g + 7 * 4096 + bloc * 512 + ksub * 32;
    short8 v0 = ldh(hp),      v1 = ldh(hp + 8);
    short8 v2 = ldh(hp + 16), v3 = ldh(hp + 24);
    TIE4("0", v0, v1, v2, v3);
    const float* wr = Wfc + (size_t)(oq * 16 + ol) * HID + ksub * 32;
    float s = 0.f;
#pragma unroll
    for (int j = 0; j < 8; ++j) {
      s += bf2f((u16)v0[j]) * wr[j];
      s += bf2f((u16)v1[j]) * wr[8 + j];
      s += bf2f((u16)v2[j]) * wr[16 + j];
      s += bf2f((u16)v3[j]) * wr[24 + j];
    }
    red[ol][ksub] = s;
    __syncthreads();
    if (tid < 16) {
      float sum = 0.f;
#pragma unroll
      for (int j = 0; j < 16; ++j) sum += red[tid][j];
      out[(size_t)(8 * g + bloc) * OUTN + oq * 16 + tid] = sum + bfc[oq * 16 + tid];
    }
  }
}

// Workspace layout (bytes):
//   [256, 4352)          one-time barrier leaves (32 x 128B)
//   [8192, 10240)        flag0[8][64] u32 (per-producer monotonic, 16 used)
//   [16384, 18432)       flag1[8][64] u32
//   [32768, 557056)      h0 rings: 8 groups x 8 slots x 8 b x 512 k bf16
//   [557056, 1081344)    h1 rings
//   [1081344, 5275648)   xg: 8 groups x 256 t x 8 b x 128 k bf16
// memset [0, 1081344) each launch (flags/rings; slot 7 = h[-1] = 0).

extern "C" void kernel_launch(void* const* d_in, const int* in_sizes, int n_in,
                              void* d_out, int out_size, void* d_ws, size_t ws_size,
                              hipStream_t stream) {
  (void)in_sizes; (void)n_in; (void)out_size; (void)ws_size;

  char* ws = (char*)d_ws;
  unsigned* leaf  = (unsigned*)(ws + 256);
  unsigned* flag0 = (unsigned*)(ws + 8192);
  unsigned* flag1 = (unsigned*)(ws + 16384);
  u16* h0r = (u16*)(ws + 32768);
  u16* h1r = (u16*)(ws + 557056);
  u16* xg  = (u16*)(ws + 1081344);

  hipMemsetAsync(d_ws, 0, 1081344, stream);

  const float* x    = (const float*)d_in[0];
  const float* Wih0 = (const float*)d_in[1];
  const float* Whh0 = (const float*)d_in[2];
  const float* bih0 = (const float*)d_in[3];
  const float* bhh0 = (const float*)d_in[4];
  const float* Wih1 = (const float*)d_in[5];
  const float* Whh1 = (const float*)d_in[6];
  const float* bih1 = (const float*)d_in[7];
  const float* bhh1 = (const float*)d_in[8];
  const float* Wfc  = (const float*)d_in[9];
  const float* bfc  = (const float*)d_in[10];
  float* out = (float*)d_out;

  void* args[] = {
    (void*)&x,
    (void*)&Wih0, (void*)&Whh0, (void*)&bih0, (void*)&bhh0,
    (void*)&Wih1, (void*)&Whh1, (void*)&bih1, (void*)&bhh1,
    (void*)&Wfc,  (void*)&bfc,
    (void*)&out,
    (void*)&leaf, (void*)&flag0, (void*)&flag1,
    (void*)&h0r, (void*)&h1r, (void*)&xg
  };
  hipError_t err = hipLaunchCooperativeKernel((const void*)lstm_groups,
                                              dim3(NWG), dim3(NT), args, 0, stream);
  if (err != hipSuccess) {
    // 256 blocks @ 1 block/CU on 256 CUs are co-resident structurally.
    hipLaunchKernelGGL(lstm_groups, dim3(NWG), dim3(NT), 0, stream,
                       x, Wih0, Whh0, bih0, bhh0, Wih1, Whh1, bih1, bhh1,
                       Wfc, bfc, out, leaf, flag0, flag1, h0r, h1r, xg);
  }
}